// Round 8
// baseline (502.277 us; speedup 1.0000x reference)
//
#include <hip/hip_runtime.h>
#include <hip/hip_bf16.h>
#include <math.h>

#define BSZ 4096
#define DIM 768
#define BK 32
#define NTILE (DIM / BK)     // 24 K-tiles
#define CSPLIT 16            // 4096/256 column panels
#define BUFSZ 32768          // per K-tile LDS: A 16KB + B 16KB

typedef __attribute__((ext_vector_type(8))) short short8;
typedef __attribute__((ext_vector_type(4))) float f32x4;

__device__ __forceinline__ unsigned short f2bf(float f) {
  unsigned u = __float_as_uint(f);
  u += 0x7fffu + ((u >> 16) & 1u);   // RNE
  return (unsigned short)(u >> 16);
}

__device__ __forceinline__ void gload16(const void* gp, const void* lp) {
  __builtin_amdgcn_global_load_lds(
      (const __attribute__((address_space(1))) unsigned int*)(size_t)gp,
      (__attribute__((address_space(3))) unsigned int*)(unsigned int)(size_t)lp,
      16, 0, 0);
}

__device__ __forceinline__ short8 lds_ld(const unsigned char* p) {
  return *(const short8*)p;
}

// device-coherent (agent-scope, L2-bypassing) accessors — NO whole-L2 fences
__device__ __forceinline__ void cstore(float* p, float v) {
  __hip_atomic_store(p, v, __ATOMIC_RELAXED, __HIP_MEMORY_SCOPE_AGENT);
}
__device__ __forceinline__ float cload(const float* p) {
  return __hip_atomic_load(p, __ATOMIC_RELAXED, __HIP_MEMORY_SCOPE_AGENT);
}

// ---------------- fp32 -> bf16 conversion (both matrices) + counter init ----
__global__ void convert_kernel(const float* __restrict__ src0,   // nl
                               const float* __restrict__ src1,   // code
                               unsigned short* __restrict__ dst0,
                               unsigned short* __restrict__ dst1,
                               unsigned int* __restrict__ cnt)
{
  if (blockIdx.x == 0 && threadIdx.x <= CSPLIT) cnt[threadIdx.x] = 0u;
  const int n4 = (BSZ * DIM) / 4;
  int i = blockIdx.x * blockDim.x + threadIdx.x;
  const float* src;
  unsigned short* dst;
  if (i < n4) { src = src0; dst = dst0; }
  else        { src = src1; dst = dst1; i -= n4; }
  float4 v = *reinterpret_cast<const float4*>(src + (size_t)i * 4);
  ushort4 o;
  o.x = f2bf(v.x); o.y = f2bf(v.y); o.z = f2bf(v.z); o.w = f2bf(v.w);
  *reinterpret_cast<ushort4*>(dst + (size_t)i * 4) = o;
}

// ---------------- fused 256x256 GEMM + per-row LSE partials -----------------
// scores[i][j] = <nl[i], code[j]>. A = nl (rows), B = code (cols).
// PREFETCH-DEPTH-2 build: BK=32, TRIPLE-buffered LDS (3x32KB=96KB, still
// 1 block/CU -> same occupancy/regs as the r7 baseline; pure A/B on depth).
// Tile u reads buf[u%3]; during tile u we issue ALL 4 staging loads for tile
// u+2 into buf[(u+2)%3] -> ~2 full tiles (~1500+ cyc) of latency coverage,
// enough for cold-HBM (~900 cyc) staging this harness's L2/L3-evicting
// resets cause. One vmcnt(4)+barrier per K-tile (24 total): end of tile u
// drains only tile u+1's 4 loads; tile u+2's stay in flight (FIFO: 8
// outstanding -> vmcnt(4)). Role-split kept: odd waves do m-half 1 first.
// LDS rows 64B; swizzle: stored 16B-block b' of row r holds global block
// b'^((r>>1)&3); frag read block = hi ^ ((lr>>1)&3)  (0 conflicts, r6 PMC).
// Cross-block LSE merge via agent-scope sc1 stores/loads (no __threadfence).
__global__ __launch_bounds__(512, 2)
void gemm_lse_kernel(const unsigned short* __restrict__ A,
                     const unsigned short* __restrict__ B,
                     float* __restrict__ pm, float* __restrict__ ps,
                     float* __restrict__ diag,
                     float* __restrict__ partial,
                     unsigned int* __restrict__ cnt,
                     float* __restrict__ out)
{
  __shared__ alignas(16) unsigned char smem[3 * BUFSZ];
  // buf v @ v*32768: A (256 rows x 64B = 16KB) @ +0, B (256 x 64B) @ +16384
  const int tid  = threadIdx.x;
  const int w    = tid >> 6;
  const int lane = tid & 63;
  const int lr   = lane & 15;
  const int hi   = lane >> 4;
  const int wm   = w >> 2;
  const int wn   = w & 3;
  const int h0   = (w & 1) << 2;   // role: first m-half (0 or 4)

  // bijective XCD swizzle: 8 XCDs each own a 4x8 sub-grid (256 % 8 == 0)
  const int id  = blockIdx.y * 16 + blockIdx.x;   // hw dispatch order, x fastest
  const int xcd = id & 7, sq = id >> 3;
  const int bx  = ((xcd & 3) << 2) | (sq & 3);    // row panel   [0,16)
  const int by  = ((xcd >> 2) << 3) | (sq >> 2);  // col panel   [0,16)
  const int i0 = bx << 8;
  const int j0 = by << 8;

  // fragment read: row r (== lr mod 16), 16B-block hi ^ ((r>>1)&3)
  const int fb    = (hi ^ ((lr >> 1) & 3)) << 4;
  const int arowb = (wm * 128 + lr) * 64;        // + m*1024
  const int browb = (wn * 64 + lr) * 64;         // + n*1024

  // staging: thread t covers row (q*128 + tid>>2), stored block tid&3 (linear
  // LDS dest tid*16); source col-block pre-swizzled: (tid&3) ^ ((tid>>3)&3)
  const int srow = tid >> 2;                               // 0..127
  const int gcol = (((tid & 3) ^ ((tid >> 3) & 3)) << 3);  // element col
  const unsigned short* pA = A + (size_t)(i0 + srow) * DIM + gcol;
  const unsigned short* pB = B + (size_t)(j0 + srow) * DIM + gcol;
  const int ldsbase = w << 10;   // wave-uniform; lane*16 added by HW

  f32x4 acc[8][4];
#pragma unroll
  for (int m = 0; m < 8; ++m)
#pragma unroll
    for (int n = 0; n < 4; ++n)
      acc[m][n] = (f32x4){0.f, 0.f, 0.f, 0.f};

  // prologue: stage tile 0 -> buf0, tile 1 -> buf1 (4 gloads each, FIFO order)
#pragma unroll
  for (int t = 0; t < 2; ++t) {
    unsigned char* bf = smem + t * BUFSZ;
    const size_t ko = (size_t)t * BK;
    gload16(pA + ko,                      bf +         ldsbase);
    gload16(pA + (size_t)128 * DIM + ko,  bf +  8192 + ldsbase);
    gload16(pB + ko,                      bf + 16384 + ldsbase);
    gload16(pB + (size_t)128 * DIM + ko,  bf + 24576 + ldsbase);
  }
  asm volatile("s_waitcnt vmcnt(4)" ::: "memory");   // tile 0 landed; tile 1 in flight
  __builtin_amdgcn_s_barrier();

#pragma unroll 3
  for (int u = 0; u < NTILE; ++u) {
    const unsigned char* la = smem + (u % 3) * BUFSZ;
    const unsigned char* lb = la + 16384;
    unsigned char* nv = smem + ((u + 2) % 3) * BUFSZ;
    const bool st = (u + 2 < NTILE);
    const size_t kn = (size_t)(u + 2) * BK;

    short8 aF[4], bF[4];
#pragma unroll
    for (int n = 0; n < 4; ++n) bF[n] = lds_ld(lb + browb + n * 1024 + fb);
#pragma unroll
    for (int m = 0; m < 4; ++m) aF[m] = lds_ld(la + arowb + (h0 + m) * 1024 + fb);
    if (st) {   // issue tile u+2's 4 staging loads (buffer last read at u-1)
      gload16(pA + kn,                      nv +         ldsbase);
      gload16(pA + (size_t)128 * DIM + kn,  nv +  8192 + ldsbase);
      gload16(pB + kn,                      nv + 16384 + ldsbase);
      gload16(pB + (size_t)128 * DIM + kn,  nv + 24576 + ldsbase);
    }
    asm volatile("s_waitcnt lgkmcnt(0)" ::: "memory");
    __builtin_amdgcn_s_setprio(1);
#pragma unroll
    for (int m = 0; m < 4; ++m)
#pragma unroll
      for (int n = 0; n < 4; ++n)
        acc[h0 + m][n] =
            __builtin_amdgcn_mfma_f32_16x16x32_bf16(aF[m], bF[n], acc[h0 + m][n], 0, 0, 0);
    __builtin_amdgcn_s_setprio(0);

    // second m-half (role order)
#pragma unroll
    for (int m = 0; m < 4; ++m) aF[m] = lds_ld(la + arowb + ((h0 ^ 4) + m) * 1024 + fb);
    asm volatile("s_waitcnt lgkmcnt(0)" ::: "memory");
    __builtin_amdgcn_s_setprio(1);
#pragma unroll
    for (int m = 0; m < 4; ++m)
#pragma unroll
      for (int n = 0; n < 4; ++n)
        acc[(h0 ^ 4) + m][n] =
            __builtin_amdgcn_mfma_f32_16x16x32_bf16(aF[m], bF[n], acc[(h0 ^ 4) + m][n], 0, 0, 0);
    __builtin_amdgcn_s_setprio(0);

    // drain tile u+1's 4 loads; keep tile u+2's 4 in flight
    if (st) asm volatile("s_waitcnt vmcnt(4)" ::: "memory");
    else    asm volatile("s_waitcnt vmcnt(0)" ::: "memory");
    __builtin_amdgcn_s_barrier();
  }

  // ---------------- epilogue: diag + per-row LSE partials ----------------
  __syncthreads();

  if (i0 == j0) {
#pragma unroll
    for (int m = 0; m < 8; ++m)
#pragma unroll
      for (int n = 0; n < 4; ++n)
#pragma unroll
        for (int rr = 0; rr < 4; ++rr) {
          const int rl = wm * 128 + m * 16 + (hi << 2) + rr;
          const int cl = wn * 64 + n * 16 + lr;
          if (rl == cl) cstore(&diag[i0 + rl], acc[m][n][rr]);
        }
  }

  float* redm = (float*)smem;            // [4][256]
  float* reds = (float*)(smem + 4096);   // [4][256]

#pragma unroll
  for (int m = 0; m < 8; ++m) {
    float mx[4], sm[4];
#pragma unroll
    for (int rr = 0; rr < 4; ++rr) {
      float v = fmaxf(fmaxf(acc[m][0][rr], acc[m][1][rr]),
                      fmaxf(acc[m][2][rr], acc[m][3][rr]));
      mx[rr] = v;
    }
#pragma unroll
    for (int sh = 1; sh < 16; sh <<= 1)
#pragma unroll
      for (int rr = 0; rr < 4; ++rr)
        mx[rr] = fmaxf(mx[rr], __shfl_xor(mx[rr], sh, 64));
#pragma unroll
    for (int rr = 0; rr < 4; ++rr) {
      float s = 0.f;
#pragma unroll
      for (int n = 0; n < 4; ++n) s += __expf(acc[m][n][rr] - mx[rr]);
      sm[rr] = s;
    }
#pragma unroll
    for (int sh = 1; sh < 16; sh <<= 1)
#pragma unroll
      for (int rr = 0; rr < 4; ++rr)
        sm[rr] += __shfl_xor(sm[rr], sh, 64);
    if (lr == 0) {
#pragma unroll
      for (int rr = 0; rr < 4; ++rr) {
        const int rl = wm * 128 + m * 16 + (hi << 2) + rr;
        redm[(wn << 8) + rl] = mx[rr];
        reds[(wn << 8) + rl] = sm[rr];
      }
    }
  }
  __syncthreads();

  if (tid < 256) {
    float m = redm[tid];
#pragma unroll
    for (int v = 1; v < 4; ++v) m = fmaxf(m, redm[(v << 8) + tid]);
    float s = 0.f;
#pragma unroll
    for (int v = 0; v < 4; ++v) s += reds[(v << 8) + tid] * __expf(redm[(v << 8) + tid] - m);
    cstore(&pm[(size_t)by * BSZ + i0 + tid], m);
    cstore(&ps[(size_t)by * BSZ + i0 + tid], s);
  }

  // ---------------- cross-block merge (split-K last-block-wins) ----------------
  // All communicated stores above are sc1 (agent-coherent, past the XCD L2).
  // Each wave drains its own stores (vmcnt(0)), barrier, then one relaxed bump.
  asm volatile("s_waitcnt vmcnt(0)" ::: "memory");
  __syncthreads();
  __shared__ unsigned int sord;
  if (tid == 0) sord = atomicAdd(&cnt[bx], 1u);
  __syncthreads();
  if (sord == CSPLIT - 1) {
    float val = 0.f;
    if (tid < 256) {
      const int row = i0 + tid;
      float mv[CSPLIT];
      float m = -INFINITY;
#pragma unroll
      for (int c = 0; c < CSPLIT; ++c) {
        mv[c] = cload(&pm[(size_t)c * BSZ + row]);
        m = fmaxf(m, mv[c]);
      }
      float s = 0.f;
#pragma unroll
      for (int c = 0; c < CSPLIT; ++c)
        s += cload(&ps[(size_t)c * BSZ + row]) * __expf(mv[c] - m);
      val = (m + __logf(s)) - cload(&diag[row]);
    }
    float* red2 = (float*)smem;   // [512]; prior smem uses are done (synced above)
    red2[tid] = val;
    __syncthreads();
    for (int off = 256; off > 0; off >>= 1) {
      if (tid < off) red2[tid] += red2[tid + off];
      __syncthreads();
    }
    if (tid == 0) {
      cstore(&partial[bx], red2[0]);
      asm volatile("s_waitcnt vmcnt(0)" ::: "memory");
      unsigned int d = atomicAdd(&cnt[CSPLIT], 1u);
      if (d == CSPLIT - 1) {
        float s = 0.f;
        for (int i = 0; i < CSPLIT; ++i) s += cload(&partial[i]);
        out[0] = s / (float)BSZ;
      }
    }
  }
}

extern "C" void kernel_launch(void* const* d_in, const int* in_sizes, int n_in,
                              void* d_out, int out_size, void* d_ws, size_t ws_size,
                              hipStream_t stream) {
  const float* code = (const float*)d_in[0];   // [BSZ][DIM]
  const float* nl   = (const float*)d_in[1];   // [BSZ][DIM]
  float* out = (float*)d_out;

  char* ws = (char*)d_ws;
  unsigned short* Abf = (unsigned short*)ws;                              // nl bf16
  unsigned short* Bbf = (unsigned short*)(ws + (size_t)BSZ * DIM * 2);    // code bf16
  float* pm   = (float*)(ws + (size_t)BSZ * DIM * 4);                     // [CSPLIT][BSZ]
  float* ps   = pm + (size_t)CSPLIT * BSZ;
  float* diag = ps + (size_t)CSPLIT * BSZ;                                // [BSZ]
  float* partial = diag + BSZ;                                            // [16]
  unsigned int* cnt = (unsigned int*)(partial + CSPLIT);                  // [17]

  const int n4 = (BSZ * DIM) / 4;
  convert_kernel<<<(2 * n4) / 256, 256, 0, stream>>>(nl, code, Abf, Bbf, cnt);

  dim3 grid(BSZ / 256, BSZ / 256);
  gemm_lse_kernel<<<grid, 512, 0, stream>>>(Abf, Bbf, pm, ps, diag, partial, cnt, out);
}

// Round 9
// 98.048 us; speedup vs baseline: 5.1227x; 5.1227x over previous
//
#include <hip/hip_runtime.h>
#include <hip/hip_bf16.h>
#include <math.h>

#define BSZ 4096
#define DIM 768
#define BK 32
#define NTILE (DIM / BK)     // 24 K-tiles
#define CSPLIT 16            // 4096/256 column panels
#define BUFSZ 32768          // per K-tile LDS: A 16KB + B 16KB

typedef __attribute__((ext_vector_type(8))) short short8;
typedef __attribute__((ext_vector_type(4))) float f32x4;

__device__ __forceinline__ unsigned short f2bf(float f) {
  unsigned u = __float_as_uint(f);
  u += 0x7fffu + ((u >> 16) & 1u);   // RNE
  return (unsigned short)(u >> 16);
}

__device__ __forceinline__ void gload16(const void* gp, const void* lp) {
  __builtin_amdgcn_global_load_lds(
      (const __attribute__((address_space(1))) unsigned int*)(size_t)gp,
      (__attribute__((address_space(3))) unsigned int*)(unsigned int)(size_t)lp,
      16, 0, 0);
}

__device__ __forceinline__ short8 lds_ld(const unsigned char* p) {
  return *(const short8*)p;
}

// device-coherent (agent-scope, L2-bypassing) accessors — NO whole-L2 fences
__device__ __forceinline__ void cstore(float* p, float v) {
  __hip_atomic_store(p, v, __ATOMIC_RELAXED, __HIP_MEMORY_SCOPE_AGENT);
}
__device__ __forceinline__ float cload(const float* p) {
  return __hip_atomic_load(p, __ATOMIC_RELAXED, __HIP_MEMORY_SCOPE_AGENT);
}

// ---------------- fp32 -> bf16 conversion (both matrices) + counter init ----
__global__ void convert_kernel(const float* __restrict__ src0,   // nl
                               const float* __restrict__ src1,   // code
                               unsigned short* __restrict__ dst0,
                               unsigned short* __restrict__ dst1,
                               unsigned int* __restrict__ cnt)
{
  if (blockIdx.x == 0 && threadIdx.x <= CSPLIT) cnt[threadIdx.x] = 0u;
  const int n4 = (BSZ * DIM) / 4;
  int i = blockIdx.x * blockDim.x + threadIdx.x;
  const float* src;
  unsigned short* dst;
  if (i < n4) { src = src0; dst = dst0; }
  else        { src = src1; dst = dst1; i -= n4; }
  float4 v = *reinterpret_cast<const float4*>(src + (size_t)i * 4);
  ushort4 o;
  o.x = f2bf(v.x); o.y = f2bf(v.y); o.z = f2bf(v.z); o.w = f2bf(v.w);
  *reinterpret_cast<ushort4*>(dst + (size_t)i * 4) = o;
}

// ---------------- fused 256x256 GEMM + per-row LSE partials -----------------
// scores[i][j] = <nl[i], code[j]>. A = nl (rows), B = code (cols).
// PREFETCH-DEPTH-2 build (r8 retry, spill-fixed): BK=32, triple-buffered LDS
// (3x32KB = 96KB, 1 block/CU). Tile u reads buf[u%3]; during tile u we issue
// all 4 staging loads for tile u+2 -> ~2 tiles (~1500 cyc) of latency
// coverage for cold-HBM staging. One vmcnt(4)+barrier per K-tile.
// ROLE SPLIT IS COMPILE-TIME (r8 bug: acc[h0+m] with runtime h0 demoted the
// whole 128-reg accumulator to scratch -> 1.6GB spill traffic, 502us. Rule
// #20.): wave-uniform if/else with both m-half orders written out statically.
// LDS rows 64B; swizzle: stored 16B-block b' of row r holds global block
// b'^((r>>1)&3); frag read block = hi ^ ((lr>>1)&3)  (0 conflicts, r6 PMC).
// Cross-block LSE merge via agent-scope sc1 stores/loads (no __threadfence).
__global__ __launch_bounds__(512, 2)
void gemm_lse_kernel(const unsigned short* __restrict__ A,
                     const unsigned short* __restrict__ B,
                     float* __restrict__ pm, float* __restrict__ ps,
                     float* __restrict__ diag,
                     float* __restrict__ partial,
                     unsigned int* __restrict__ cnt,
                     float* __restrict__ out)
{
  __shared__ alignas(16) unsigned char smem[3 * BUFSZ];
  // buf v @ v*32768: A (256 rows x 64B = 16KB) @ +0, B (256 x 64B) @ +16384
  const int tid  = threadIdx.x;
  const int w    = tid >> 6;
  const int lane = tid & 63;
  const int lr   = lane & 15;
  const int hi   = lane >> 4;
  const int wm   = w >> 2;
  const int wn   = w & 3;
  const bool odd = (w & 1) != 0;   // role: m-half order (wave-uniform)

  // bijective XCD swizzle: 8 XCDs each own a 4x8 sub-grid (256 % 8 == 0)
  const int id  = blockIdx.y * 16 + blockIdx.x;   // hw dispatch order, x fastest
  const int xcd = id & 7, sq = id >> 3;
  const int bx  = ((xcd & 3) << 2) | (sq & 3);    // row panel   [0,16)
  const int by  = ((xcd >> 2) << 3) | (sq >> 2);  // col panel   [0,16)
  const int i0 = bx << 8;
  const int j0 = by << 8;

  // fragment read: row r (== lr mod 16), 16B-block hi ^ ((r>>1)&3)
  const int fb    = (hi ^ ((lr >> 1) & 3)) << 4;
  const int arowb = (wm * 128 + lr) * 64;        // + m*1024
  const int browb = (wn * 64 + lr) * 64;         // + n*1024

  // staging: thread t covers row (q*128 + tid>>2), stored block tid&3 (linear
  // LDS dest tid*16); source col-block pre-swizzled: (tid&3) ^ ((tid>>3)&3)
  const int srow = tid >> 2;                               // 0..127
  const int gcol = (((tid & 3) ^ ((tid >> 3) & 3)) << 3);  // element col
  const unsigned short* pA = A + (size_t)(i0 + srow) * DIM + gcol;
  const unsigned short* pB = B + (size_t)(j0 + srow) * DIM + gcol;
  const int ldsbase = w << 10;   // wave-uniform; lane*16 added by HW

  f32x4 acc[8][4];
#pragma unroll
  for (int m = 0; m < 8; ++m)
#pragma unroll
    for (int n = 0; n < 4; ++n)
      acc[m][n] = (f32x4){0.f, 0.f, 0.f, 0.f};

  // prologue: stage tile 0 -> buf0, tile 1 -> buf1 (4 gloads each, FIFO order)
#pragma unroll
  for (int t = 0; t < 2; ++t) {
    unsigned char* bf = smem + t * BUFSZ;
    const size_t ko = (size_t)t * BK;
    gload16(pA + ko,                      bf +         ldsbase);
    gload16(pA + (size_t)128 * DIM + ko,  bf +  8192 + ldsbase);
    gload16(pB + ko,                      bf + 16384 + ldsbase);
    gload16(pB + (size_t)128 * DIM + ko,  bf + 24576 + ldsbase);
  }
  asm volatile("s_waitcnt vmcnt(4)" ::: "memory");   // tile 0 landed; tile 1 in flight
  __builtin_amdgcn_s_barrier();

#pragma unroll 3
  for (int u = 0; u < NTILE; ++u) {
    const unsigned char* la = smem + (u % 3) * BUFSZ;
    const unsigned char* lb = la + 16384;
    unsigned char* nv = smem + ((u + 2) % 3) * BUFSZ;
    const bool st = (u + 2 < NTILE);
    const size_t kn = (size_t)(u + 2) * BK;

    short8 aF[4], bF[4];
#pragma unroll
    for (int n = 0; n < 4; ++n) bF[n] = lds_ld(lb + browb + n * 1024 + fb);
    if (st) {   // issue tile u+2's 4 staging loads (buffer last read at u-1)
      gload16(pA + kn,                      nv +         ldsbase);
      gload16(pA + (size_t)128 * DIM + kn,  nv +  8192 + ldsbase);
      gload16(pB + kn,                      nv + 16384 + ldsbase);
      gload16(pB + (size_t)128 * DIM + kn,  nv + 24576 + ldsbase);
    }

    if (!odd) {
      // ---- m-half 0 then 1 (ALL indices compile-time constant) ----
#pragma unroll
      for (int m = 0; m < 4; ++m) aF[m] = lds_ld(la + arowb + m * 1024 + fb);
      asm volatile("s_waitcnt lgkmcnt(0)" ::: "memory");
      __builtin_amdgcn_s_setprio(1);
#pragma unroll
      for (int m = 0; m < 4; ++m)
#pragma unroll
        for (int n = 0; n < 4; ++n)
          acc[m][n] = __builtin_amdgcn_mfma_f32_16x16x32_bf16(aF[m], bF[n], acc[m][n], 0, 0, 0);
      __builtin_amdgcn_s_setprio(0);
#pragma unroll
      for (int m = 0; m < 4; ++m) aF[m] = lds_ld(la + arowb + (4 + m) * 1024 + fb);
      asm volatile("s_waitcnt lgkmcnt(0)" ::: "memory");
      __builtin_amdgcn_s_setprio(1);
#pragma unroll
      for (int m = 0; m < 4; ++m)
#pragma unroll
        for (int n = 0; n < 4; ++n)
          acc[4 + m][n] = __builtin_amdgcn_mfma_f32_16x16x32_bf16(aF[m], bF[n], acc[4 + m][n], 0, 0, 0);
      __builtin_amdgcn_s_setprio(0);
    } else {
      // ---- m-half 1 then 0 ----
#pragma unroll
      for (int m = 0; m < 4; ++m) aF[m] = lds_ld(la + arowb + (4 + m) * 1024 + fb);
      asm volatile("s_waitcnt lgkmcnt(0)" ::: "memory");
      __builtin_amdgcn_s_setprio(1);
#pragma unroll
      for (int m = 0; m < 4; ++m)
#pragma unroll
        for (int n = 0; n < 4; ++n)
          acc[4 + m][n] = __builtin_amdgcn_mfma_f32_16x16x32_bf16(aF[m], bF[n], acc[4 + m][n], 0, 0, 0);
      __builtin_amdgcn_s_setprio(0);
#pragma unroll
      for (int m = 0; m < 4; ++m) aF[m] = lds_ld(la + arowb + m * 1024 + fb);
      asm volatile("s_waitcnt lgkmcnt(0)" ::: "memory");
      __builtin_amdgcn_s_setprio(1);
#pragma unroll
      for (int m = 0; m < 4; ++m)
#pragma unroll
        for (int n = 0; n < 4; ++n)
          acc[m][n] = __builtin_amdgcn_mfma_f32_16x16x32_bf16(aF[m], bF[n], acc[m][n], 0, 0, 0);
      __builtin_amdgcn_s_setprio(0);
    }

    // drain tile u+1's 4 loads; keep tile u+2's 4 in flight
    if (st) asm volatile("s_waitcnt vmcnt(4)" ::: "memory");
    else    asm volatile("s_waitcnt vmcnt(0)" ::: "memory");
    __builtin_amdgcn_s_barrier();
  }

  // ---------------- epilogue: diag + per-row LSE partials ----------------
  __syncthreads();

  if (i0 == j0) {
#pragma unroll
    for (int m = 0; m < 8; ++m)
#pragma unroll
      for (int n = 0; n < 4; ++n)
#pragma unroll
        for (int rr = 0; rr < 4; ++rr) {
          const int rl = wm * 128 + m * 16 + (hi << 2) + rr;
          const int cl = wn * 64 + n * 16 + lr;
          if (rl == cl) cstore(&diag[i0 + rl], acc[m][n][rr]);
        }
  }

  float* redm = (float*)smem;            // [4][256]
  float* reds = (float*)(smem + 4096);   // [4][256]

#pragma unroll
  for (int m = 0; m < 8; ++m) {
    float mx[4], sm[4];
#pragma unroll
    for (int rr = 0; rr < 4; ++rr) {
      float v = fmaxf(fmaxf(acc[m][0][rr], acc[m][1][rr]),
                      fmaxf(acc[m][2][rr], acc[m][3][rr]));
      mx[rr] = v;
    }
#pragma unroll
    for (int sh = 1; sh < 16; sh <<= 1)
#pragma unroll
      for (int rr = 0; rr < 4; ++rr)
        mx[rr] = fmaxf(mx[rr], __shfl_xor(mx[rr], sh, 64));
#pragma unroll
    for (int rr = 0; rr < 4; ++rr) {
      float s = 0.f;
#pragma unroll
      for (int n = 0; n < 4; ++n) s += __expf(acc[m][n][rr] - mx[rr]);
      sm[rr] = s;
    }
#pragma unroll
    for (int sh = 1; sh < 16; sh <<= 1)
#pragma unroll
      for (int rr = 0; rr < 4; ++rr)
        sm[rr] += __shfl_xor(sm[rr], sh, 64);
    if (lr == 0) {
#pragma unroll
      for (int rr = 0; rr < 4; ++rr) {
        const int rl = wm * 128 + m * 16 + (hi << 2) + rr;
        redm[(wn << 8) + rl] = mx[rr];
        reds[(wn << 8) + rl] = sm[rr];
      }
    }
  }
  __syncthreads();

  if (tid < 256) {
    float m = redm[tid];
#pragma unroll
    for (int v = 1; v < 4; ++v) m = fmaxf(m, redm[(v << 8) + tid]);
    float s = 0.f;
#pragma unroll
    for (int v = 0; v < 4; ++v) s += reds[(v << 8) + tid] * __expf(redm[(v << 8) + tid] - m);
    cstore(&pm[(size_t)by * BSZ + i0 + tid], m);
    cstore(&ps[(size_t)by * BSZ + i0 + tid], s);
  }

  // ---------------- cross-block merge (split-K last-block-wins) ----------------
  // All communicated stores above are sc1 (agent-coherent, past the XCD L2).
  // Each wave drains its own stores (vmcnt(0)), barrier, then one relaxed bump.
  asm volatile("s_waitcnt vmcnt(0)" ::: "memory");
  __syncthreads();
  __shared__ unsigned int sord;
  if (tid == 0) sord = atomicAdd(&cnt[bx], 1u);
  __syncthreads();
  if (sord == CSPLIT - 1) {
    float val = 0.f;
    if (tid < 256) {
      const int row = i0 + tid;
      float mv[CSPLIT];
      float m = -INFINITY;
#pragma unroll
      for (int c = 0; c < CSPLIT; ++c) {
        mv[c] = cload(&pm[(size_t)c * BSZ + row]);
        m = fmaxf(m, mv[c]);
      }
      float s = 0.f;
#pragma unroll
      for (int c = 0; c < CSPLIT; ++c)
        s += cload(&ps[(size_t)c * BSZ + row]) * __expf(mv[c] - m);
      val = (m + __logf(s)) - cload(&diag[row]);
    }
    float* red2 = (float*)smem;   // [512]; prior smem uses are done (synced above)
    red2[tid] = val;
    __syncthreads();
    for (int off = 256; off > 0; off >>= 1) {
      if (tid < off) red2[tid] += red2[tid + off];
      __syncthreads();
    }
    if (tid == 0) {
      cstore(&partial[bx], red2[0]);
      asm volatile("s_waitcnt vmcnt(0)" ::: "memory");
      unsigned int d = atomicAdd(&cnt[CSPLIT], 1u);
      if (d == CSPLIT - 1) {
        float s = 0.f;
        for (int i = 0; i < CSPLIT; ++i) s += cload(&partial[i]);
        out[0] = s / (float)BSZ;
      }
    }
  }
}

extern "C" void kernel_launch(void* const* d_in, const int* in_sizes, int n_in,
                              void* d_out, int out_size, void* d_ws, size_t ws_size,
                              hipStream_t stream) {
  const float* code = (const float*)d_in[0];   // [BSZ][DIM]
  const float* nl   = (const float*)d_in[1];   // [BSZ][DIM]
  float* out = (float*)d_out;

  char* ws = (char*)d_ws;
  unsigned short* Abf = (unsigned short*)ws;                              // nl bf16
  unsigned short* Bbf = (unsigned short*)(ws + (size_t)BSZ * DIM * 2);    // code bf16
  float* pm   = (float*)(ws + (size_t)BSZ * DIM * 4);                     // [CSPLIT][BSZ]
  float* ps   = pm + (size_t)CSPLIT * BSZ;
  float* diag = ps + (size_t)CSPLIT * BSZ;                                // [BSZ]
  float* partial = diag + BSZ;                                            // [16]
  unsigned int* cnt = (unsigned int*)(partial + CSPLIT);                  // [17]

  const int n4 = (BSZ * DIM) / 4;
  convert_kernel<<<(2 * n4) / 256, 256, 0, stream>>>(nl, code, Abf, Bbf, cnt);

  dim3 grid(BSZ / 256, BSZ / 256);
  gemm_lse_kernel<<<grid, 512, 0, stream>>>(Abf, Bbf, pm, ps, diag, partial, cnt, out);
}

// Round 10
// 45.375 us; speedup vs baseline: 11.0695x; 2.1609x over previous
//
#include <hip/hip_runtime.h>
#include <hip/hip_bf16.h>
#include <math.h>

#define BSZ 4096
#define DIM 768
#define BK 64
#define NTILE (DIM / BK)     // 12 K-tiles
#define CSPLIT 16            // 4096/256 column panels

typedef __attribute__((ext_vector_type(8))) short short8;
typedef __attribute__((ext_vector_type(4))) float f32x4;

__device__ __forceinline__ unsigned short f2bf(float f) {
  unsigned u = __float_as_uint(f);
  u += 0x7fffu + ((u >> 16) & 1u);   // RNE
  return (unsigned short)(u >> 16);
}

__device__ __forceinline__ void gload16(const void* gp, const void* lp) {
  __builtin_amdgcn_global_load_lds(
      (const __attribute__((address_space(1))) unsigned int*)(size_t)gp,
      (__attribute__((address_space(3))) unsigned int*)(unsigned int)(size_t)lp,
      16, 0, 0);
}

__device__ __forceinline__ short8 lds_ld(const unsigned char* p) {
  return *(const short8*)p;
}

// device-coherent (agent-scope, L2-bypassing) accessors — NO whole-L2 fences
__device__ __forceinline__ void cstore(float* p, float v) {
  __hip_atomic_store(p, v, __ATOMIC_RELAXED, __HIP_MEMORY_SCOPE_AGENT);
}
__device__ __forceinline__ float cload(const float* p) {
  return __hip_atomic_load(p, __ATOMIC_RELAXED, __HIP_MEMORY_SCOPE_AGENT);
}

// ---------------- fp32 -> bf16 conversion (both matrices) + counter init ----
__global__ void convert_kernel(const float* __restrict__ src0,   // nl
                               const float* __restrict__ src1,   // code
                               unsigned short* __restrict__ dst0,
                               unsigned short* __restrict__ dst1,
                               unsigned int* __restrict__ cnt)
{
  if (blockIdx.x == 0 && threadIdx.x <= CSPLIT) cnt[threadIdx.x] = 0u;
  const int n4 = (BSZ * DIM) / 4;
  int i = blockIdx.x * blockDim.x + threadIdx.x;
  const float* src;
  unsigned short* dst;
  if (i < n4) { src = src0; dst = dst0; }
  else        { src = src1; dst = dst1; i -= n4; }
  float4 v = *reinterpret_cast<const float4*>(src + (size_t)i * 4);
  ushort4 o;
  o.x = f2bf(v.x); o.y = f2bf(v.y); o.z = f2bf(v.z); o.w = f2bf(v.w);
  *reinterpret_cast<ushort4*>(dst + (size_t)i * 4) = o;
}

// ---------------- fused 256x256 GEMM + per-row LSE partials -----------------
// scores[i][j] = <nl[i], code[j]>. A = nl (rows), B = code (cols).
// 8 waves = 2M x 4N; wave (wm,wn) owns rows [wm*128,+128) x cols [wn*64,+64).
// ROLE-SPLIT build (m218b mechanism): waves of odd w process k-chunk 1 first,
// even w k-chunk 0 first -> at any instant half the waves are in ds_read
// while half are in MFMA (reads/MFMA overlap across waves instead of
// lockstep clumping). This REQUIRES dropping the per-phase barriers; the only
// sync is ONE vmcnt(0)+s_barrier per K-tile (12 total, was 96), which is all
// correctness needs: reads hit buf c, staging writes hit buf c^1.
// NOTE (r9 lesson): role enters ONLY as a value-select (fbp). mh = pp&1 is
// compile-time because role is even — acc indices stay static (rule #20);
// the K-loop body is branch-free (r9's if/else diamond demoted acc->scratch).
// acc element order: role-1 waves accumulate k1 before k0 (ulp-level only).
// Cross-block LSE merge via agent-scope sc1 stores/loads (no __threadfence).
__global__ __launch_bounds__(512, 2)
void gemm_lse_kernel(const unsigned short* __restrict__ A,
                     const unsigned short* __restrict__ B,
                     float* __restrict__ pm, float* __restrict__ ps,
                     float* __restrict__ diag,
                     float* __restrict__ partial,
                     unsigned int* __restrict__ cnt,
                     float* __restrict__ out)
{
  __shared__ alignas(16) unsigned char smem[131072];
  // bufA[c] @ c*32768 (256 rows x 128B); bufB[c] @ 65536 + c*32768
  const int tid  = threadIdx.x;
  const int w    = tid >> 6;
  const int lane = tid & 63;
  const int lr   = lane & 15;
  const int hi   = lane >> 4;
  const int wm   = w >> 2;
  const int wn   = w & 3;
  const int role = (w & 1) << 1;   // 0 or 2: phase rotation (k-chunk ping-pong)

  // bijective XCD swizzle: 8 XCDs each own a 4x8 sub-grid (256 % 8 == 0)
  const int id  = blockIdx.y * 16 + blockIdx.x;   // hw dispatch order, x fastest
  const int xcd = id & 7, sq = id >> 3;
  const int bx  = ((xcd & 3) << 2) | (sq & 3);    // row panel   [0,16)
  const int by  = ((xcd >> 2) << 3) | (sq >> 2);  // col panel   [0,16)
  const int i0 = bx << 8;
  const int j0 = by << 8;

  // swizzled 16B-block byte offset within a 128B row (row&7 == lr&7 for frag rows)
  const int fb0 = (hi ^ (lr & 7)) << 4;          // k-chunk 0
  const int fb1 = ((4 + hi) ^ (lr & 7)) << 4;    // k-chunk 1
  const int arowb = (wm * 128 + lr) * 128;       // + m*2048
  const int browb = (wn * 64 + lr) * 128;        // + n*2048

  // staging: thread t covers row srow (per 64-row chunk q) at swizzled block
  const int srow = tid >> 3;                               // 0..63
  const int gcol = ((tid & 7) ^ (srow & 7)) << 3;          // element col
  const unsigned short* pA = A + (size_t)(i0 + srow) * DIM + gcol;
  const unsigned short* pB = B + (size_t)(j0 + srow) * DIM + gcol;
  const int ldsbase = w << 10;   // wave-uniform; +q*8192; lane*16 added by HW

  f32x4 acc[8][4];
#pragma unroll
  for (int m = 0; m < 8; ++m)
#pragma unroll
    for (int n = 0; n < 4; ++n)
      acc[m][n] = (f32x4){0.f, 0.f, 0.f, 0.f};

  // prologue: stage tile 0 into buffer 0
#pragma unroll
  for (int q = 0; q < 4; ++q) {
    gload16(pA + (size_t)(q * 64) * DIM, smem + q * 8192 + ldsbase);
    gload16(pB + (size_t)(q * 64) * DIM, smem + 65536 + q * 8192 + ldsbase);
  }
  asm volatile("s_waitcnt vmcnt(0)" ::: "memory");
  __builtin_amdgcn_s_barrier();

#pragma unroll 2
  for (int u = 0; u < NTILE; ++u) {
    const int c = u & 1;
    const unsigned char* la = smem + c * 32768;
    const unsigned char* lb = smem + 65536 + c * 32768;
    unsigned char* na = smem + (c ^ 1) * 32768;
    unsigned char* nb = smem + 65536 + (c ^ 1) * 32768;
    const bool st = (u + 1 < NTILE);
    const size_t kn = (size_t)(u + 1) * BK;   // next tile's K offset (elements)

    short8 aF[4], bF[4];

#pragma unroll
    for (int pp = 0; pp < 4; ++pp) {
      const int p  = (pp + role) & 3;   // role 0: 0,1,2,3   role 2: 2,3,0,1
      const int mh = p & 1;             // m-half == pp & 1 (role is even) -> static
      const int kc = p >> 1;            // k-chunk (runtime, value-select only)
      const int fbp = kc ? fb1 : fb0;

      if (pp == 0 || pp == 2) {         // k-chunk changed -> reload B frags
#pragma unroll
        for (int n = 0; n < 4; ++n) bF[n] = lds_ld(lb + browb + n * 2048 + fbp);
      }
#pragma unroll
      for (int m = 0; m < 4; ++m)
        aF[m] = lds_ld(la + arowb + (mh * 4 + m) * 2048 + fbp);

      if (pp == 0 && st) {              // issue ALL staging for tile u+1 early
#pragma unroll
        for (int q = 0; q < 4; ++q) {
          gload16(pB + (size_t)(q * 64) * DIM + kn, nb + q * 8192 + ldsbase);
          gload16(pA + (size_t)(q * 64) * DIM + kn, na + q * 8192 + ldsbase);
        }
      }

      __builtin_amdgcn_s_setprio(1);
#pragma unroll
      for (int m = 0; m < 4; ++m)
#pragma unroll
        for (int n = 0; n < 4; ++n)
          acc[mh * 4 + m][n] =
              __builtin_amdgcn_mfma_f32_16x16x32_bf16(aF[m], bF[n], acc[mh * 4 + m][n], 0, 0, 0);
      __builtin_amdgcn_s_setprio(0);
    }

    // single sync point per K-tile: staged writes landed, all waves done reading
    asm volatile("s_waitcnt vmcnt(0)" ::: "memory");
    __builtin_amdgcn_s_barrier();
  }

  // ---------------- epilogue: diag + per-row LSE partials ----------------
  __syncthreads();

  if (i0 == j0) {
#pragma unroll
    for (int m = 0; m < 8; ++m)
#pragma unroll
      for (int n = 0; n < 4; ++n)
#pragma unroll
        for (int rr = 0; rr < 4; ++rr) {
          const int rl = wm * 128 + m * 16 + (hi << 2) + rr;
          const int cl = wn * 64 + n * 16 + lr;
          if (rl == cl) cstore(&diag[i0 + rl], acc[m][n][rr]);
        }
  }

  float* redm = (float*)smem;            // [4][256]
  float* reds = (float*)(smem + 4096);   // [4][256]

#pragma unroll
  for (int m = 0; m < 8; ++m) {
    float mx[4], sm[4];
#pragma unroll
    for (int rr = 0; rr < 4; ++rr) {
      float v = fmaxf(fmaxf(acc[m][0][rr], acc[m][1][rr]),
                      fmaxf(acc[m][2][rr], acc[m][3][rr]));
      mx[rr] = v;
    }
#pragma unroll
    for (int sh = 1; sh < 16; sh <<= 1)
#pragma unroll
      for (int rr = 0; rr < 4; ++rr)
        mx[rr] = fmaxf(mx[rr], __shfl_xor(mx[rr], sh, 64));
#pragma unroll
    for (int rr = 0; rr < 4; ++rr) {
      float s = 0.f;
#pragma unroll
      for (int n = 0; n < 4; ++n) s += __expf(acc[m][n][rr] - mx[rr]);
      sm[rr] = s;
    }
#pragma unroll
    for (int sh = 1; sh < 16; sh <<= 1)
#pragma unroll
      for (int rr = 0; rr < 4; ++rr)
        sm[rr] += __shfl_xor(sm[rr], sh, 64);
    if (lr == 0) {
#pragma unroll
      for (int rr = 0; rr < 4; ++rr) {
        const int rl = wm * 128 + m * 16 + (hi << 2) + rr;
        redm[(wn << 8) + rl] = mx[rr];
        reds[(wn << 8) + rl] = sm[rr];
      }
    }
  }
  __syncthreads();

  if (tid < 256) {
    float m = redm[tid];
#pragma unroll
    for (int v = 1; v < 4; ++v) m = fmaxf(m, redm[(v << 8) + tid]);
    float s = 0.f;
#pragma unroll
    for (int v = 0; v < 4; ++v) s += reds[(v << 8) + tid] * __expf(redm[(v << 8) + tid] - m);
    cstore(&pm[(size_t)by * BSZ + i0 + tid], m);
    cstore(&ps[(size_t)by * BSZ + i0 + tid], s);
  }

  // ---------------- cross-block merge (split-K last-block-wins) ----------------
  // All communicated stores above are sc1 (agent-coherent, past the XCD L2).
  // Each wave drains its own stores (vmcnt(0)), barrier, then one relaxed bump.
  asm volatile("s_waitcnt vmcnt(0)" ::: "memory");
  __syncthreads();
  __shared__ unsigned int sord;
  if (tid == 0) sord = atomicAdd(&cnt[bx], 1u);
  __syncthreads();
  if (sord == CSPLIT - 1) {
    float val = 0.f;
    if (tid < 256) {
      const int row = i0 + tid;
      float mv[CSPLIT];
      float m = -INFINITY;
#pragma unroll
      for (int c = 0; c < CSPLIT; ++c) {
        mv[c] = cload(&pm[(size_t)c * BSZ + row]);
        m = fmaxf(m, mv[c]);
      }
      float s = 0.f;
#pragma unroll
      for (int c = 0; c < CSPLIT; ++c)
        s += cload(&ps[(size_t)c * BSZ + row]) * __expf(mv[c] - m);
      val = (m + __logf(s)) - cload(&diag[row]);
    }
    float* red2 = (float*)smem;   // [512]; prior smem uses are done (synced above)
    red2[tid] = val;
    __syncthreads();
    for (int off = 256; off > 0; off >>= 1) {
      if (tid < off) red2[tid] += red2[tid + off];
      __syncthreads();
    }
    if (tid == 0) {
      cstore(&partial[bx], red2[0]);
      asm volatile("s_waitcnt vmcnt(0)" ::: "memory");
      unsigned int d = atomicAdd(&cnt[CSPLIT], 1u);
      if (d == CSPLIT - 1) {
        float s = 0.f;
        for (int i = 0; i < CSPLIT; ++i) s += cload(&partial[i]);
        out[0] = s / (float)BSZ;
      }
    }
  }
}

extern "C" void kernel_launch(void* const* d_in, const int* in_sizes, int n_in,
                              void* d_out, int out_size, void* d_ws, size_t ws_size,
                              hipStream_t stream) {
  const float* code = (const float*)d_in[0];   // [BSZ][DIM]
  const float* nl   = (const float*)d_in[1];   // [BSZ][DIM]
  float* out = (float*)d_out;

  char* ws = (char*)d_ws;
  unsigned short* Abf = (unsigned short*)ws;                              // nl bf16
  unsigned short* Bbf = (unsigned short*)(ws + (size_t)BSZ * DIM * 2);    // code bf16
  float* pm   = (float*)(ws + (size_t)BSZ * DIM * 4);                     // [CSPLIT][BSZ]
  float* ps   = pm + (size_t)CSPLIT * BSZ;
  float* diag = ps + (size_t)CSPLIT * BSZ;                                // [BSZ]
  float* partial = diag + BSZ;                                            // [16]
  unsigned int* cnt = (unsigned int*)(partial + CSPLIT);                  // [17]

  const int n4 = (BSZ * DIM) / 4;
  convert_kernel<<<(2 * n4) / 256, 256, 0, stream>>>(nl, code, Abf, Bbf, cnt);

  dim3 grid(BSZ / 256, BSZ / 256);
  gemm_lse_kernel<<<grid, 512, 0, stream>>>(Abf, Bbf, pm, ps, diag, partial, cnt, out);
}